// Round 4
// baseline (436.756 us; speedup 1.0000x reference)
//
#include <hip/hip_runtime.h>
#include <hip/hip_bf16.h>

#define N_NODESC 50000
#define N_EDGESC 1600000
#define NGC 1024
#define NPC 8
#define NBIN 196          // dst>>8 buckets (256 nodes each)
#define NBLKE 391         // edge chunks of 4096

typedef __attribute__((ext_vector_type(8))) short bf16x8;
typedef __attribute__((ext_vector_type(4))) float f32x4;

__device__ inline ushort f2bf(float f) {
  union { float f; uint u; } v; v.f = f;
  uint u = v.u;
  u += 0x7FFF + ((u >> 16) & 1);
  return (ushort)(u >> 16);
}
__device__ inline float bflo(uint u) {
  union { uint u; float f; } v; v.u = u << 16; return v.f;
}
__device__ inline float bfhi(uint u) {
  union { uint u; float f; } v; v.u = u & 0xFFFF0000u; return v.f;
}

// ---------------- fused weight prep ----------------
// bid 0..127: qa1 fold (2 rows/blk); 128..255: qa2; 256..303: lin1 pad->96; 304..431: lin2
__global__ __launch_bounds__(256) void prep_all(
    const float* __restrict__ qa1w, const float* __restrict__ qa2w,
    const float* __restrict__ lin1w, const float* __restrict__ lin2w,
    ushort* __restrict__ qe1, ushort* __restrict__ qe2,
    ushort* __restrict__ l1w, ushort* __restrict__ l2w) {
  int bid = blockIdx.x, t = threadIdx.x;
  if (bid < 256) {
    const float* qw = (bid < 128) ? qa1w : qa2w;
    ushort* eff = (bid < 128) ? qe1 : qe2;
    int k = (bid & 127) * 2 + (t >> 7);
    int j = t & 127;
    const float* r = qw + (size_t)k * 256;
    float v;
    if (j < 64) v = r[j] + r[128 + j] + r[192 + j];
    else { int j2 = j - 64; v = r[64 + j2] + r[128 + j2] + 2.0f * r[192 + j2]; }
    eff[(size_t)k * 128 + j] = f2bf(v);
  } else if (bid < 304) {
    int i = (bid - 256) * 256 + t;  // < 12288 = 128*96
    int r = i / 96, c = i - r * 96;
    l1w[i] = (c < 68) ? f2bf(lin1w[(size_t)r * 68 + c]) : (ushort)0;
  } else {
    int r = bid - 304;
    l2w[(size_t)r * 256 + t] = f2bf(lin2w[(size_t)r * 256 + t]);
  }
}

// node features: [N,96] bf16 (cols 68..95 zero), grid-stride elementwise
__global__ __launch_bounds__(256) void feat_kernel(const int* __restrict__ x,
                                                   const float* __restrict__ e24,
                                                   const float* __restrict__ e72,
                                                   ushort* __restrict__ feat) {
  int stride = gridDim.x * 256;
  for (int i = blockIdx.x * 256 + threadIdx.x; i < N_NODESC * 96; i += stride) {
    int n = i / 96, t = i - n * 96;
    float v = 0.f;
    if (t < 4) v = (float)x[n * 4 + t];
    else if (t < 36) { int kk = t - 4;  int f = kk >> 3, c = kk & 7; v = e24[(x[n * 4 + f] % 24) * 8 + c]; }
    else if (t < 68) { int kk = t - 36; int f = kk >> 3, c = kk & 7; v = e72[(x[n * 4 + f] % 72) * 8 + c]; }
    feat[i] = f2bf(v);
  }
}

// ---------------- CSR build: bucketed two-pass sort ----------------
__global__ __launch_bounds__(256) void csr_hist(const int* __restrict__ dst,
                                                int* __restrict__ bh, int E) {
  __shared__ int hist[NBIN];
  int t = threadIdx.x, blk = blockIdx.x;
  if (t < NBIN) hist[t] = 0;
  __syncthreads();
  int base = blk * 4096;
#pragma unroll
  for (int i = 0; i < 16; ++i) {
    int idx = base + i * 256 + t;
    if (idx < E) atomicAdd(&hist[dst[idx] >> 8], 1);
  }
  __syncthreads();
  if (t < NBIN) bh[(size_t)t * NBLKE + blk] = hist[t];
}

__global__ __launch_bounds__(64) void csr_scan_bins(int* __restrict__ bh, int* __restrict__ bt) {
  int bin = blockIdx.x;
  int lane = threadIdx.x;
  int carry = 0;
  int* row = bh + (size_t)bin * NBLKE;
  for (int c = 0; c < NBLKE; c += 64) {
    int j = c + lane;
    int v = (j < NBLKE) ? row[j] : 0;
    int incl = v;
#pragma unroll
    for (int off = 1; off < 64; off <<= 1) {
      int u = __shfl_up(incl, off, 64);
      if (lane >= off) incl += u;
    }
    if (j < NBLKE) row[j] = carry + incl - v;
    carry += __shfl(incl, 63, 64);
  }
  if (lane == 0) bt[bin] = carry;
}

// scatter packed edges into bucket-grouped tmp; bucket bases derived from bt in-block
__global__ __launch_bounds__(256) void csr_scatter(const int* __restrict__ src,
                                                   const int* __restrict__ dst,
                                                   const int* __restrict__ bh,
                                                   const int* __restrict__ bt,
                                                   uint* __restrict__ tmp, int E) {
  __shared__ int sc[256];
  __shared__ int cur[NBIN];
  int t = threadIdx.x, blk = blockIdx.x;
  int v = (t < NBIN) ? bt[t] : 0;
  sc[t] = v;
  __syncthreads();
  for (int off = 1; off < 256; off <<= 1) {
    int u = (t >= off) ? sc[t - off] : 0;
    __syncthreads();
    sc[t] += u;
    __syncthreads();
  }
  if (t < NBIN) cur[t] = (sc[t] - v) + bh[(size_t)t * NBLKE + blk];
  __syncthreads();
  int base = blk * 4096;
#pragma unroll
  for (int i = 0; i < 16; ++i) {
    int idx = base + i * 256 + t;
    if (idx < E) {
      int d = dst[idx];
      uint p = ((uint)d << 16) | (uint)src[idx];
      int pos = atomicAdd(&cur[d >> 8], 1);
      tmp[pos] = p;
    }
  }
}

// per-bucket counting sort by node -> elist (ushort src) + rp
__global__ __launch_bounds__(256) void csr_bucket_sort(const uint* __restrict__ tmp,
                                                       const int* __restrict__ bt,
                                                       ushort* __restrict__ elist,
                                                       int* __restrict__ rp) {
  __shared__ int sc[256];
  __shared__ int cnt[256];
  int b = blockIdx.x, t = threadIdx.x;
  int v = (t < NBIN) ? bt[t] : 0;
  sc[t] = v;
  __syncthreads();
  for (int off = 1; off < 256; off <<= 1) {
    int u = (t >= off) ? sc[t - off] : 0;
    __syncthreads();
    sc[t] += u;
    __syncthreads();
  }
  int base = (b == 0) ? 0 : sc[b - 1];
  int end = sc[b];
  int total = sc[NBIN - 1];
  __syncthreads();
  cnt[t] = 0;
  __syncthreads();
  for (int i = base + t; i < end; i += 256)
    atomicAdd(&cnt[(tmp[i] >> 16) & 255], 1);
  __syncthreads();
  int cv = cnt[t];
  sc[t] = cv;
  __syncthreads();
  for (int off = 1; off < 256; off <<= 1) {
    int u = (t >= off) ? sc[t - off] : 0;
    __syncthreads();
    sc[t] += u;
    __syncthreads();
  }
  int excl = sc[t] - cv;
  int node = (b << 8) + t;
  if (node < N_NODESC) rp[node] = base + excl;
  if (b == NBIN - 1 && t == 0) rp[N_NODESC] = total;
  cnt[t] = base + excl;  // global cursor
  __syncthreads();
  for (int i = base + t; i < end; i += 256) {
    uint p = tmp[i];
    int pos = atomicAdd(&cnt[(p >> 16) & 255], 1);
    elist[pos] = (ushort)(p & 0xFFFFu);
  }
}

// ---------------- MFMA GEMM: C[M,NC] = act(A @ W^T + b) ---------------------
// A_CB/C_CB: col-block-major layout [(col>>5)*M + row]*32 + (col&31) (bf16)
template <int A_CB, int C_CB>
__global__ __launch_bounds__(256) void mfma_gemm(
    const ushort* __restrict__ A, const ushort* __restrict__ W,
    const float* __restrict__ bias, ushort* __restrict__ C,
    int M, int K, int NC, int relu) {
  int lane = threadIdx.x & 63;
  int wv = threadIdx.x >> 6;
  int rbase = blockIdx.x * 128 + wv * 32;
  int colt = blockIdx.y * 128;
  int r16 = lane & 15;
  int kg = (lane >> 4) * 8;

  f32x4 acc[2][8];
#pragma unroll
  for (int m = 0; m < 2; ++m)
#pragma unroll
    for (int n = 0; n < 8; ++n) acc[m][n] = (f32x4){0.f, 0.f, 0.f, 0.f};

  for (int k0 = 0; k0 < K; k0 += 32) {
    bf16x8 a[2], b[8];
#pragma unroll
    for (int m = 0; m < 2; ++m) {
      int rr = rbase + m * 16 + r16;
      if (rr >= M) rr = M - 1;
      const ushort* ap = A_CB ? (A + ((size_t)(k0 >> 5) * M + rr) * 32 + kg)
                              : (A + (size_t)rr * K + k0 + kg);
      a[m] = *(const bf16x8*)ap;
    }
#pragma unroll
    for (int n = 0; n < 8; ++n) {
      b[n] = *(const bf16x8*)(W + (size_t)(colt + n * 16 + r16) * K + k0 + kg);
    }
#pragma unroll
    for (int m = 0; m < 2; ++m)
#pragma unroll
      for (int n = 0; n < 8; ++n)
        acc[m][n] = __builtin_amdgcn_mfma_f32_16x16x32_bf16(a[m], b[n], acc[m][n], 0, 0, 0);
  }

  int rowoff = (lane >> 4) * 4;
#pragma unroll
  for (int m = 0; m < 2; ++m) {
#pragma unroll
    for (int j = 0; j < 4; ++j) {
      int row = rbase + m * 16 + rowoff + j;
      if (row >= M) continue;
#pragma unroll
      for (int n = 0; n < 8; ++n) {
        int col = colt + n * 16 + r16;
        float v = acc[m][n][j] + bias[col];
        if (relu) v = fmaxf(v, 0.f);
        size_t idx = C_CB ? ((size_t)(col >> 5) * M + row) * 32 + (col & 31)
                          : (size_t)row * NC + col;
        C[idx] = f2bf(v);
      }
    }
  }
}

// ---------------- aggregation, col-sliced: 4 temporal passes ----------------
// lx/h2 layout: [pass][N][16] uints (= 32 bf16 cols per pass).
// Block = 4 waves; wave handles 2 nodes; within wave: 4 edge-slots x 16 col-lanes.
__global__ __launch_bounds__(256) void aggregate_cb(const uint* __restrict__ lx,
                                                    const int* __restrict__ rp,
                                                    const ushort* __restrict__ elist,
                                                    uint* __restrict__ h2) {
  const int BPP = N_NODESC / 8;  // 6250 blocks per pass
  int gid = blockIdx.x;
  int pass = gid / BPP;
  int nb = gid - pass * BPP;
  int wv = threadIdx.x >> 6, lane = threadIdx.x & 63;
  int eg = lane >> 4, cp = lane & 15;
  const uint* T = lx + (size_t)pass * N_NODESC * 16;
  uint* O = h2 + (size_t)pass * N_NODESC * 16;
#pragma unroll
  for (int r = 0; r < 2; ++r) {
    int n = nb * 8 + wv * 2 + r;
    int beg = rp[n], end = rp[n + 1];
    uint su = T[(size_t)n * 16 + cp];
    float a0 = 0.f, a1 = 0.f;
    int e = beg + eg;
    for (; e + 4 < end; e += 8) {
      int s0 = __builtin_nontemporal_load(elist + e);
      int s1 = __builtin_nontemporal_load(elist + e + 4);
      uint u0 = T[(size_t)s0 * 16 + cp];
      uint u1 = T[(size_t)s1 * 16 + cp];
      a0 += bflo(u0) + bflo(u1);
      a1 += bfhi(u0) + bfhi(u1);
    }
    if (e < end) {
      int s0 = __builtin_nontemporal_load(elist + e);
      uint u0 = T[(size_t)s0 * 16 + cp];
      a0 += bflo(u0);
      a1 += bfhi(u0);
    }
    a0 += __shfl_xor(a0, 16);
    a0 += __shfl_xor(a0, 32);
    a1 += __shfl_xor(a1, 16);
    a1 += __shfl_xor(a1, 32);
    if (eg == 0) {
      uint w = (uint)f2bf(a0 + 2.f * bflo(su)) | ((uint)f2bf(a1 + 2.f * bfhi(su)) << 16);
      __builtin_nontemporal_store(w, O + (size_t)n * 16 + cp);
    }
  }
}

// ---------------- global mean pool (batch sorted), bf16 input ---------------
__global__ __launch_bounds__(128) void pool2(const uint* __restrict__ h,
                                             const int* __restrict__ batch,
                                             float* __restrict__ g) {
  int gg = blockIdx.x;
  int j = threadIdx.x;
  int lo = 0, hi = N_NODESC;
  while (lo < hi) { int mid = (lo + hi) >> 1; if (batch[mid] < gg) lo = mid + 1; else hi = mid; }
  int beg = lo;
  hi = N_NODESC;
  while (lo < hi) { int mid = (lo + hi) >> 1; if (batch[mid] < gg + 1) lo = mid + 1; else hi = mid; }
  int end = lo;
  float a0 = 0.f, a1 = 0.f;
  for (int n = beg; n < end; ++n) {
    uint u = h[(size_t)n * 128 + j];
    a0 += bflo(u);
    a1 += bfhi(u);
  }
  float c = fmaxf((float)(end - beg), 1.0f);
  g[(size_t)gg * 256 + 2 * j] = a0 / c;
  g[(size_t)gg * 256 + 2 * j + 1] = a1 / c;
}

// ---------------- per-property heads (8 graphs per block) -------------------
__global__ __launch_bounds__(128) void head_kernel(const float* __restrict__ g,
    const float* __restrict__ w1, const float* __restrict__ b1,
    const float* __restrict__ w2, const float* __restrict__ b2,
    float* __restrict__ out) {
  int p = blockIdx.y;
  int g0 = blockIdx.x * 8;
  int t = threadIdx.x;
  __shared__ float gs[8][256];
  for (int i = t; i < 8 * 256; i += 128)
    gs[i >> 8][i & 255] = g[(size_t)(g0 + (i >> 8)) * 256 + (i & 255)];
  __syncthreads();
  const float4* w4 = (const float4*)(w1 + ((size_t)p * 128 + t) * 256);
  float bv = b1[p * 128 + t];
  float acc[8];
#pragma unroll
  for (int q = 0; q < 8; ++q) acc[q] = bv;
  for (int d4 = 0; d4 < 64; ++d4) {
    float4 wv = w4[d4];
#pragma unroll
    for (int q = 0; q < 8; ++q) {
      acc[q] += gs[q][d4 * 4 + 0] * wv.x + gs[q][d4 * 4 + 1] * wv.y +
                gs[q][d4 * 4 + 2] * wv.z + gs[q][d4 * 4 + 3] * wv.w;
    }
  }
  float w2v = w2[p * 128 + t];
  __shared__ float red[2][8];
  int wave = t >> 6, lane = t & 63;
#pragma unroll
  for (int q = 0; q < 8; ++q) {
    float v = fmaxf(acc[q], 0.f) * w2v;
    for (int o = 32; o > 0; o >>= 1) v += __shfl_down(v, o, 64);
    if (lane == 0) red[wave][q] = v;
  }
  __syncthreads();
  if (t < 8) out[(size_t)(g0 + t) * 8 + p] = red[0][t] + red[1][t] + b2[p];
}

extern "C" void kernel_launch(void* const* d_in, const int* in_sizes, int n_in,
                              void* d_out, int out_size, void* d_ws, size_t ws_size,
                              hipStream_t stream) {
  const int*   x     = (const int*)d_in[0];
  const int*   ei    = (const int*)d_in[1];
  const int*   batch = (const int*)d_in[2];
  const float* emb24 = (const float*)d_in[3];
  const float* emb72 = (const float*)d_in[4];
  const float* lin1w = (const float*)d_in[5];
  const float* lin1b = (const float*)d_in[6];
  const float* qa1w  = (const float*)d_in[7];
  const float* qa1b  = (const float*)d_in[8];
  const float* lin2w = (const float*)d_in[9];
  const float* lin2b = (const float*)d_in[10];
  const float* qa2w  = (const float*)d_in[11];
  const float* qa2b  = (const float*)d_in[12];
  const float* hw1   = (const float*)d_in[13];
  const float* hb1   = (const float*)d_in[14];
  const float* hw2   = (const float*)d_in[15];
  const float* hb2   = (const float*)d_in[16];
  float* out = (float*)d_out;

  const int* srcv = ei;
  const int* dstv = ei + N_EDGESC;

  char* wsb = (char*)d_ws;
  size_t off = 0;
  auto alloc = [&](size_t b) { char* p = wsb + off; off += (b + 255) & ~(size_t)255; return p; };
  ushort* feat  = (ushort*)alloc((size_t)N_NODESC * 96 * 2);
  ushort* linx  = (ushort*)alloc((size_t)N_NODESC * 128 * 2);   // CB layout [4][N][32]
  ushort* h2    = (ushort*)alloc((size_t)N_NODESC * 128 * 2);   // CB layout
  ushort* h     = (ushort*)alloc((size_t)N_NODESC * 256 * 2);   // row-major
  float*  gbuf  = (float*)alloc((size_t)NGC * 256 * 4);
  ushort* qe1   = (ushort*)alloc(256 * 128 * 2);
  ushort* qe2   = (ushort*)alloc(256 * 128 * 2);
  ushort* l1w   = (ushort*)alloc(128 * 96 * 2);
  ushort* l2w   = (ushort*)alloc(128 * 256 * 2);
  int*    rp    = (int*)alloc((size_t)(N_NODESC + 1) * 4);
  ushort* elist = (ushort*)alloc((size_t)N_EDGESC * 2);
  int*    bh    = (int*)alloc((size_t)NBIN * NBLKE * 4);
  int*    bt    = (int*)alloc((size_t)NBIN * 4);
  uint*   tmp   = (uint*)h;  // alias: h unused until after first aggregation

  // weight prep + features
  prep_all<<<432, 256, 0, stream>>>(qa1w, qa2w, lin1w, lin2w, qe1, qe2, l1w, l2w);
  feat_kernel<<<2048, 256, 0, stream>>>(x, emb24, emb72, feat);

  // CSR build: bucketed two-pass sort
  csr_hist<<<NBLKE, 256, 0, stream>>>(dstv, bh, N_EDGESC);
  csr_scan_bins<<<NBIN, 64, 0, stream>>>(bh, bt);
  csr_scatter<<<NBLKE, 256, 0, stream>>>(srcv, dstv, bh, bt, tmp, N_EDGESC);
  csr_bucket_sort<<<NBIN, 256, 0, stream>>>(tmp, bt, elist, rp);

  int gm = (N_NODESC + 127) / 128;

  // layer 1
  mfma_gemm<0, 1><<<dim3(gm, 1), 256, 0, stream>>>(feat, l1w, lin1b, linx, N_NODESC, 96, 128, 0);
  aggregate_cb<<<(N_NODESC / 8) * 4, 256, 0, stream>>>((const uint*)linx, rp, elist, (uint*)h2);
  mfma_gemm<1, 0><<<dim3(gm, 2), 256, 0, stream>>>(h2, qe1, qa1b, h, N_NODESC, 128, 256, 1);

  // layer 2
  mfma_gemm<0, 1><<<dim3(gm, 1), 256, 0, stream>>>(h, l2w, lin2b, linx, N_NODESC, 256, 128, 0);
  aggregate_cb<<<(N_NODESC / 8) * 4, 256, 0, stream>>>((const uint*)linx, rp, elist, (uint*)h2);
  mfma_gemm<1, 0><<<dim3(gm, 2), 256, 0, stream>>>(h2, qe2, qa2b, h, N_NODESC, 128, 256, 1);

  // pool + heads
  pool2<<<NGC, 128, 0, stream>>>((const uint*)h, batch, gbuf);
  head_kernel<<<dim3(NGC / 8, NPC), 128, 0, stream>>>(gbuf, hw1, hb1, hw2, hb2, out);
}

// Round 5
// 337.224 us; speedup vs baseline: 1.2951x; 1.2951x over previous
//
#include <hip/hip_runtime.h>
#include <hip/hip_bf16.h>

#define N_NODESC 50000
#define N_EDGESC 1600000
#define NGC 1024
#define NPC 8
#define NBIN 196          // dst>>8 buckets (256 nodes each)
#define NBLKE 391         // edge chunks of 4096

typedef __attribute__((ext_vector_type(8))) short bf16x8;
typedef __attribute__((ext_vector_type(4))) float f32x4;

__device__ inline ushort f2bf(float f) {
  union { float f; uint u; } v; v.f = f;
  uint u = v.u;
  u += 0x7FFF + ((u >> 16) & 1);
  return (ushort)(u >> 16);
}
__device__ inline float bflo(uint u) {
  union { uint u; float f; } v; v.u = u << 16; return v.f;
}
__device__ inline float bfhi(uint u) {
  union { uint u; float f; } v; v.u = u & 0xFFFF0000u; return v.f;
}

// ---------------- fused weight prep ----------------
// bid 0..127: qa1 fold (2 rows/blk); 128..255: qa2; 256..303: lin1 pad->96; 304..431: lin2
__global__ __launch_bounds__(256) void prep_all(
    const float* __restrict__ qa1w, const float* __restrict__ qa2w,
    const float* __restrict__ lin1w, const float* __restrict__ lin2w,
    ushort* __restrict__ qe1, ushort* __restrict__ qe2,
    ushort* __restrict__ l1w, ushort* __restrict__ l2w) {
  int bid = blockIdx.x, t = threadIdx.x;
  if (bid < 256) {
    const float* qw = (bid < 128) ? qa1w : qa2w;
    ushort* eff = (bid < 128) ? qe1 : qe2;
    int k = (bid & 127) * 2 + (t >> 7);
    int j = t & 127;
    const float* r = qw + (size_t)k * 256;
    float v;
    if (j < 64) v = r[j] + r[128 + j] + r[192 + j];
    else { int j2 = j - 64; v = r[64 + j2] + r[128 + j2] + 2.0f * r[192 + j2]; }
    eff[(size_t)k * 128 + j] = f2bf(v);
  } else if (bid < 304) {
    int i = (bid - 256) * 256 + t;  // < 12288 = 128*96
    int r = i / 96, c = i - r * 96;
    l1w[i] = (c < 68) ? f2bf(lin1w[(size_t)r * 68 + c]) : (ushort)0;
  } else {
    int r = bid - 304;
    l2w[(size_t)r * 256 + t] = f2bf(lin2w[(size_t)r * 256 + t]);
  }
}

// node features: [N,96] bf16 (cols 68..95 zero), grid-stride elementwise
__global__ __launch_bounds__(256) void feat_kernel(const int* __restrict__ x,
                                                   const float* __restrict__ e24,
                                                   const float* __restrict__ e72,
                                                   ushort* __restrict__ feat) {
  int stride = gridDim.x * 256;
  for (int i = blockIdx.x * 256 + threadIdx.x; i < N_NODESC * 96; i += stride) {
    int n = i / 96, t = i - n * 96;
    float v = 0.f;
    if (t < 4) v = (float)x[n * 4 + t];
    else if (t < 36) { int kk = t - 4;  int f = kk >> 3, c = kk & 7; v = e24[(x[n * 4 + f] % 24) * 8 + c]; }
    else if (t < 68) { int kk = t - 36; int f = kk >> 3, c = kk & 7; v = e72[(x[n * 4 + f] % 72) * 8 + c]; }
    feat[i] = f2bf(v);
  }
}

// ---------------- CSR build: bucketed two-pass sort ----------------
__global__ __launch_bounds__(256) void csr_hist(const int* __restrict__ dst,
                                                int* __restrict__ bh, int E) {
  __shared__ int hist[NBIN];
  int t = threadIdx.x, blk = blockIdx.x;
  if (t < NBIN) hist[t] = 0;
  __syncthreads();
  int base = blk * 4096;
#pragma unroll
  for (int i = 0; i < 16; ++i) {
    int idx = base + i * 256 + t;
    if (idx < E) atomicAdd(&hist[dst[idx] >> 8], 1);
  }
  __syncthreads();
  if (t < NBIN) bh[(size_t)t * NBLKE + blk] = hist[t];
}

__global__ __launch_bounds__(64) void csr_scan_bins(int* __restrict__ bh, int* __restrict__ bt) {
  int bin = blockIdx.x;
  int lane = threadIdx.x;
  int carry = 0;
  int* row = bh + (size_t)bin * NBLKE;
  for (int c = 0; c < NBLKE; c += 64) {
    int j = c + lane;
    int v = (j < NBLKE) ? row[j] : 0;
    int incl = v;
#pragma unroll
    for (int off = 1; off < 64; off <<= 1) {
      int u = __shfl_up(incl, off, 64);
      if (lane >= off) incl += u;
    }
    if (j < NBLKE) row[j] = carry + incl - v;
    carry += __shfl(incl, 63, 64);
  }
  if (lane == 0) bt[bin] = carry;
}

// scatter packed edges into bucket-grouped tmp; bucket bases derived from bt in-block
__global__ __launch_bounds__(256) void csr_scatter(const int* __restrict__ src,
                                                   const int* __restrict__ dst,
                                                   const int* __restrict__ bh,
                                                   const int* __restrict__ bt,
                                                   uint* __restrict__ tmp, int E) {
  __shared__ int sc[256];
  __shared__ int cur[NBIN];
  int t = threadIdx.x, blk = blockIdx.x;
  int v = (t < NBIN) ? bt[t] : 0;
  sc[t] = v;
  __syncthreads();
  for (int off = 1; off < 256; off <<= 1) {
    int u = (t >= off) ? sc[t - off] : 0;
    __syncthreads();
    sc[t] += u;
    __syncthreads();
  }
  if (t < NBIN) cur[t] = (sc[t] - v) + bh[(size_t)t * NBLKE + blk];
  __syncthreads();
  int base = blk * 4096;
#pragma unroll
  for (int i = 0; i < 16; ++i) {
    int idx = base + i * 256 + t;
    if (idx < E) {
      int d = dst[idx];
      uint p = ((uint)d << 16) | (uint)src[idx];
      int pos = atomicAdd(&cur[d >> 8], 1);
      tmp[pos] = p;
    }
  }
}

// per-bucket counting sort by node -> elist (ushort src) + rp
__global__ __launch_bounds__(256) void csr_bucket_sort(const uint* __restrict__ tmp,
                                                       const int* __restrict__ bt,
                                                       ushort* __restrict__ elist,
                                                       int* __restrict__ rp) {
  __shared__ int sc[256];
  __shared__ int cnt[256];
  int b = blockIdx.x, t = threadIdx.x;
  int v = (t < NBIN) ? bt[t] : 0;
  sc[t] = v;
  __syncthreads();
  for (int off = 1; off < 256; off <<= 1) {
    int u = (t >= off) ? sc[t - off] : 0;
    __syncthreads();
    sc[t] += u;
    __syncthreads();
  }
  int base = (b == 0) ? 0 : sc[b - 1];
  int end = sc[b];
  int total = sc[NBIN - 1];
  __syncthreads();
  cnt[t] = 0;
  __syncthreads();
  for (int i = base + t; i < end; i += 256)
    atomicAdd(&cnt[(tmp[i] >> 16) & 255], 1);
  __syncthreads();
  int cv = cnt[t];
  sc[t] = cv;
  __syncthreads();
  for (int off = 1; off < 256; off <<= 1) {
    int u = (t >= off) ? sc[t - off] : 0;
    __syncthreads();
    sc[t] += u;
    __syncthreads();
  }
  int excl = sc[t] - cv;
  int node = (b << 8) + t;
  if (node < N_NODESC) rp[node] = base + excl;
  if (b == NBIN - 1 && t == 0) rp[N_NODESC] = total;
  cnt[t] = base + excl;  // global cursor
  __syncthreads();
  for (int i = base + t; i < end; i += 256) {
    uint p = tmp[i];
    int pos = atomicAdd(&cnt[(p >> 16) & 255], 1);
    elist[pos] = (ushort)(p & 0xFFFFu);
  }
}

// ---------------- MFMA GEMM: C[M,NC] = act(A[M,K] @ W[NC,K]^T + b) ----------
// grid.x = ceil(M/128), grid.y = NC/128; 256 threads = 4 waves, each wave 32 rows.
__global__ __launch_bounds__(256) void mfma_gemm(
    const ushort* __restrict__ A, const ushort* __restrict__ W,
    const float* __restrict__ bias, ushort* __restrict__ C,
    int M, int K, int NC, int relu) {
  int lane = threadIdx.x & 63;
  int wv = threadIdx.x >> 6;
  int rbase = blockIdx.x * 128 + wv * 32;
  int colt = blockIdx.y * 128;
  int r16 = lane & 15;
  int kg = (lane >> 4) * 8;

  f32x4 acc[2][8];
#pragma unroll
  for (int m = 0; m < 2; ++m)
#pragma unroll
    for (int n = 0; n < 8; ++n) acc[m][n] = (f32x4){0.f, 0.f, 0.f, 0.f};

  for (int k0 = 0; k0 < K; k0 += 32) {
    bf16x8 a[2], b[8];
#pragma unroll
    for (int m = 0; m < 2; ++m) {
      int rr = rbase + m * 16 + r16;
      if (rr >= M) rr = M - 1;
      a[m] = *(const bf16x8*)(A + (size_t)rr * K + k0 + kg);
    }
#pragma unroll
    for (int n = 0; n < 8; ++n) {
      b[n] = *(const bf16x8*)(W + (size_t)(colt + n * 16 + r16) * K + k0 + kg);
    }
#pragma unroll
    for (int m = 0; m < 2; ++m)
#pragma unroll
      for (int n = 0; n < 8; ++n)
        acc[m][n] = __builtin_amdgcn_mfma_f32_16x16x32_bf16(a[m], b[n], acc[m][n], 0, 0, 0);
  }

  int rowoff = (lane >> 4) * 4;
#pragma unroll
  for (int m = 0; m < 2; ++m) {
#pragma unroll
    for (int j = 0; j < 4; ++j) {
      int row = rbase + m * 16 + rowoff + j;
      if (row >= M) continue;
#pragma unroll
      for (int n = 0; n < 8; ++n) {
        int col = colt + n * 16 + r16;
        float v = acc[m][n][j] + bias[col];
        if (relu) v = fmaxf(v, 0.f);
        C[(size_t)row * NC + col] = f2bf(v);
      }
    }
  }
}

// ---------------- fused qa1 + lin2: O = (relu(A@W1^T+b1)) @ W2^T + b2 -------
// A [M][128], W1 [256][128], W2 [128][256], O [M][128]. 64-row tiles.
// Intermediate 64x256 bf16 tile lives in swizzled LDS.
__global__ __launch_bounds__(256) void fused_qa_lin(
    const ushort* __restrict__ A, const ushort* __restrict__ W1,
    const float* __restrict__ B1, const ushort* __restrict__ W2,
    const float* __restrict__ B2, ushort* __restrict__ O, int M) {
  __shared__ ushort hs[64 * 256];  // 32KB; byte addr ^= (lrow&7)<<4
  int lane = threadIdx.x & 63;
  int wv = threadIdx.x >> 6;
  int rbase = blockIdx.x * 64 + wv * 16;  // each wave owns 16 rows
  int r16 = lane & 15;
  int kg = (lane >> 4) * 8;
  int rowoff = (lane >> 4) * 4;

  // ---- GEMM1 (K=128 -> 256 cols, two halves of 128) ----
#pragma unroll
  for (int half = 0; half < 2; ++half) {
    f32x4 acc[8];
#pragma unroll
    for (int n = 0; n < 8; ++n) acc[n] = (f32x4){0.f, 0.f, 0.f, 0.f};
    for (int k0 = 0; k0 < 128; k0 += 32) {
      int rr = rbase + r16;
      if (rr >= M) rr = M - 1;
      bf16x8 a = *(const bf16x8*)(A + (size_t)rr * 128 + k0 + kg);
      bf16x8 b[8];
#pragma unroll
      for (int n = 0; n < 8; ++n)
        b[n] = *(const bf16x8*)(W1 + (size_t)(half * 128 + n * 16 + r16) * 128 + k0 + kg);
#pragma unroll
      for (int n = 0; n < 8; ++n)
        acc[n] = __builtin_amdgcn_mfma_f32_16x16x32_bf16(a, b[n], acc[n], 0, 0, 0);
    }
    // epilogue -> LDS (bias + relu + bf16), swizzled
#pragma unroll
    for (int j = 0; j < 4; ++j) {
      int lrow = wv * 16 + rowoff + j;
#pragma unroll
      for (int n = 0; n < 8; ++n) {
        int col = half * 128 + n * 16 + r16;
        float v = fmaxf(acc[n][j] + B1[col], 0.f);
        int byte = (lrow * 512 + col * 2) ^ ((lrow & 7) << 4);
        *(ushort*)((char*)hs + byte) = f2bf(v);
      }
    }
  }
  __syncthreads();

  // ---- GEMM2 (K=256 -> 128 cols) ----
  f32x4 acc2[8];
#pragma unroll
  for (int n = 0; n < 8; ++n) acc2[n] = (f32x4){0.f, 0.f, 0.f, 0.f};
  int lrow_a = wv * 16 + r16;
  for (int k0 = 0; k0 < 256; k0 += 32) {
    int byte = (lrow_a * 512 + (k0 + kg) * 2) ^ ((lrow_a & 7) << 4);
    bf16x8 a = *(const bf16x8*)((const char*)hs + byte);
    bf16x8 b[8];
#pragma unroll
    for (int n = 0; n < 8; ++n)
      b[n] = *(const bf16x8*)(W2 + (size_t)(n * 16 + r16) * 256 + k0 + kg);
#pragma unroll
    for (int n = 0; n < 8; ++n)
      acc2[n] = __builtin_amdgcn_mfma_f32_16x16x32_bf16(a, b[n], acc2[n], 0, 0, 0);
  }
#pragma unroll
  for (int j = 0; j < 4; ++j) {
    int row = rbase + rowoff + j;
    if (row >= M) continue;
#pragma unroll
    for (int n = 0; n < 8; ++n) {
      int col = n * 16 + r16;
      O[(size_t)row * 128 + col] = f2bf(acc2[n][j] + B2[col]);
    }
  }
}

// ---------------- aggregation: h2[n] = 2*linx[n] + sum_{e->n} linx[src] -----
__global__ __launch_bounds__(256) void aggregate2(const uint* __restrict__ lx,
                                                  const int* __restrict__ rp,
                                                  const ushort* __restrict__ elist,
                                                  uint* __restrict__ h2) {
  int wv = threadIdx.x >> 6, lane = threadIdx.x & 63;
  int n = blockIdx.x * 4 + wv;
  int beg = rp[n], end = rp[n + 1];
  uint u = lx[(size_t)n * 64 + lane];
  float a0 = 2.f * bflo(u), a1 = 2.f * bfhi(u);
  int e = beg;
  for (; e + 8 <= end; e += 8) {
    int s0 = elist[e], s1 = elist[e + 1], s2 = elist[e + 2], s3 = elist[e + 3];
    int s4 = elist[e + 4], s5 = elist[e + 5], s6 = elist[e + 6], s7 = elist[e + 7];
    uint u0 = lx[(size_t)s0 * 64 + lane];
    uint u1 = lx[(size_t)s1 * 64 + lane];
    uint u2 = lx[(size_t)s2 * 64 + lane];
    uint u3 = lx[(size_t)s3 * 64 + lane];
    uint u4 = lx[(size_t)s4 * 64 + lane];
    uint u5 = lx[(size_t)s5 * 64 + lane];
    uint u6 = lx[(size_t)s6 * 64 + lane];
    uint u7 = lx[(size_t)s7 * 64 + lane];
    a0 += bflo(u0) + bflo(u1) + bflo(u2) + bflo(u3);
    a1 += bfhi(u0) + bfhi(u1) + bfhi(u2) + bfhi(u3);
    a0 += bflo(u4) + bflo(u5) + bflo(u6) + bflo(u7);
    a1 += bfhi(u4) + bfhi(u5) + bfhi(u6) + bfhi(u7);
  }
  for (; e < end; ++e) {
    uint u0 = lx[(size_t)elist[e] * 64 + lane];
    a0 += bflo(u0);
    a1 += bfhi(u0);
  }
  h2[(size_t)n * 64 + lane] = (uint)f2bf(a0) | ((uint)f2bf(a1) << 16);
}

// ---------------- global mean pool (batch sorted), bf16 input ---------------
__global__ __launch_bounds__(128) void pool2(const uint* __restrict__ h,
                                             const int* __restrict__ batch,
                                             float* __restrict__ g) {
  int gg = blockIdx.x;
  int j = threadIdx.x;
  int lo = 0, hi = N_NODESC;
  while (lo < hi) { int mid = (lo + hi) >> 1; if (batch[mid] < gg) lo = mid + 1; else hi = mid; }
  int beg = lo;
  hi = N_NODESC;
  while (lo < hi) { int mid = (lo + hi) >> 1; if (batch[mid] < gg + 1) lo = mid + 1; else hi = mid; }
  int end = lo;
  float a0 = 0.f, a1 = 0.f;
  for (int n = beg; n < end; ++n) {
    uint u = h[(size_t)n * 128 + j];
    a0 += bflo(u);
    a1 += bfhi(u);
  }
  float c = fmaxf((float)(end - beg), 1.0f);
  g[(size_t)gg * 256 + 2 * j] = a0 / c;
  g[(size_t)gg * 256 + 2 * j + 1] = a1 / c;
}

// ---------------- per-property heads (8 graphs per block) -------------------
__global__ __launch_bounds__(128) void head_kernel(const float* __restrict__ g,
    const float* __restrict__ w1, const float* __restrict__ b1,
    const float* __restrict__ w2, const float* __restrict__ b2,
    float* __restrict__ out) {
  int p = blockIdx.y;
  int g0 = blockIdx.x * 8;
  int t = threadIdx.x;
  __shared__ float gs[8][256];
  for (int i = t; i < 8 * 256; i += 128)
    gs[i >> 8][i & 255] = g[(size_t)(g0 + (i >> 8)) * 256 + (i & 255)];
  __syncthreads();
  const float4* w4 = (const float4*)(w1 + ((size_t)p * 128 + t) * 256);
  float bv = b1[p * 128 + t];
  float acc[8];
#pragma unroll
  for (int q = 0; q < 8; ++q) acc[q] = bv;
  for (int d4 = 0; d4 < 64; ++d4) {
    float4 wv = w4[d4];
#pragma unroll
    for (int q = 0; q < 8; ++q) {
      acc[q] += gs[q][d4 * 4 + 0] * wv.x + gs[q][d4 * 4 + 1] * wv.y +
                gs[q][d4 * 4 + 2] * wv.z + gs[q][d4 * 4 + 3] * wv.w;
    }
  }
  float w2v = w2[p * 128 + t];
  __shared__ float red[2][8];
  int wave = t >> 6, lane = t & 63;
#pragma unroll
  for (int q = 0; q < 8; ++q) {
    float v = fmaxf(acc[q], 0.f) * w2v;
    for (int o = 32; o > 0; o >>= 1) v += __shfl_down(v, o, 64);
    if (lane == 0) red[wave][q] = v;
  }
  __syncthreads();
  if (t < 8) out[(size_t)(g0 + t) * 8 + p] = red[0][t] + red[1][t] + b2[p];
}

extern "C" void kernel_launch(void* const* d_in, const int* in_sizes, int n_in,
                              void* d_out, int out_size, void* d_ws, size_t ws_size,
                              hipStream_t stream) {
  const int*   x     = (const int*)d_in[0];
  const int*   ei    = (const int*)d_in[1];
  const int*   batch = (const int*)d_in[2];
  const float* emb24 = (const float*)d_in[3];
  const float* emb72 = (const float*)d_in[4];
  const float* lin1w = (const float*)d_in[5];
  const float* lin1b = (const float*)d_in[6];
  const float* qa1w  = (const float*)d_in[7];
  const float* qa1b  = (const float*)d_in[8];
  const float* lin2w = (const float*)d_in[9];
  const float* lin2b = (const float*)d_in[10];
  const float* qa2w  = (const float*)d_in[11];
  const float* qa2b  = (const float*)d_in[12];
  const float* hw1   = (const float*)d_in[13];
  const float* hb1   = (const float*)d_in[14];
  const float* hw2   = (const float*)d_in[15];
  const float* hb2   = (const float*)d_in[16];
  float* out = (float*)d_out;

  const int* srcv = ei;
  const int* dstv = ei + N_EDGESC;

  char* wsb = (char*)d_ws;
  size_t off = 0;
  auto alloc = [&](size_t b) { char* p = wsb + off; off += (b + 255) & ~(size_t)255; return p; };
  ushort* feat  = (ushort*)alloc((size_t)N_NODESC * 96 * 2);
  ushort* linx  = (ushort*)alloc((size_t)N_NODESC * 128 * 2);   // row-major [N][128]
  ushort* h2    = (ushort*)alloc((size_t)N_NODESC * 128 * 2);   // row-major
  ushort* h     = (ushort*)alloc((size_t)N_NODESC * 256 * 2);   // row-major (layer-2 out)
  float*  gbuf  = (float*)alloc((size_t)NGC * 256 * 4);
  ushort* qe1   = (ushort*)alloc(256 * 128 * 2);
  ushort* qe2   = (ushort*)alloc(256 * 128 * 2);
  ushort* l1w   = (ushort*)alloc(128 * 96 * 2);
  ushort* l2w   = (ushort*)alloc(128 * 256 * 2);
  int*    rp    = (int*)alloc((size_t)(N_NODESC + 1) * 4);
  ushort* elist = (ushort*)alloc((size_t)N_EDGESC * 2);
  int*    bh    = (int*)alloc((size_t)NBIN * NBLKE * 4);
  int*    bt    = (int*)alloc((size_t)NBIN * 4);
  uint*   tmp   = (uint*)h;  // alias: h not written until qa2 (after CSR done)

  // weight prep + features
  prep_all<<<432, 256, 0, stream>>>(qa1w, qa2w, lin1w, lin2w, qe1, qe2, l1w, l2w);
  feat_kernel<<<2048, 256, 0, stream>>>(x, emb24, emb72, feat);

  // CSR build: bucketed two-pass sort
  csr_hist<<<NBLKE, 256, 0, stream>>>(dstv, bh, N_EDGESC);
  csr_scan_bins<<<NBIN, 64, 0, stream>>>(bh, bt);
  csr_scatter<<<NBLKE, 256, 0, stream>>>(srcv, dstv, bh, bt, tmp, N_EDGESC);
  csr_bucket_sort<<<NBIN, 256, 0, stream>>>(tmp, bt, elist, rp);

  int gm = (N_NODESC + 127) / 128;

  // layer 1: lin1
  mfma_gemm<<<dim3(gm, 1), 256, 0, stream>>>(feat, l1w, lin1b, linx, N_NODESC, 96, 128, 0);
  aggregate2<<<N_NODESC / 4, 256, 0, stream>>>((const uint*)linx, rp, elist, (uint*)h2);
  // fused qa1 + lin2: h2 -> linx (layer-2 lin output), h never materialized
  fused_qa_lin<<<(N_NODESC + 63) / 64, 256, 0, stream>>>(h2, qe1, qa1b, l2w, lin2b, linx, N_NODESC);
  aggregate2<<<N_NODESC / 4, 256, 0, stream>>>((const uint*)linx, rp, elist, (uint*)h2);
  mfma_gemm<<<dim3(gm, 2), 256, 0, stream>>>(h2, qe2, qa2b, h, N_NODESC, 128, 256, 1);

  // pool + heads
  pool2<<<NGC, 128, 0, stream>>>((const uint*)h, batch, gbuf);
  head_kernel<<<dim3(NGC / 8, NPC), 128, 0, stream>>>(gbuf, hw1, hb1, hw2, hb2, out);
}

// Round 6
// 270.292 us; speedup vs baseline: 1.6159x; 1.2476x over previous
//
#include <hip/hip_runtime.h>
#include <hip/hip_bf16.h>

#define N_NODESC 50000
#define N_EDGESC 1600000
#define NGC 1024
#define NPC 8
#define NBIN 196          // dst>>8 buckets (256 nodes each)
#define NBLKE 391         // edge chunks of 4096

typedef __attribute__((ext_vector_type(8))) short bf16x8;
typedef __attribute__((ext_vector_type(4))) float f32x4;

__device__ inline ushort f2bf(float f) {
  union { float f; uint u; } v; v.f = f;
  uint u = v.u;
  u += 0x7FFF + ((u >> 16) & 1);
  return (ushort)(u >> 16);
}
__device__ inline float bflo(uint u) {
  union { uint u; float f; } v; v.u = u << 16; return v.f;
}
__device__ inline float bfhi(uint u) {
  union { uint u; float f; } v; v.u = u & 0xFFFF0000u; return v.f;
}

// ---------------- fused prep: weights + features + edge histogram ----------
// bid 0..255: qa folds; 256..303: lin1 pad; 304..431: lin2; 432..1455: feat;
// 1456..1846: csr_hist chunk (bid-1456)
__global__ __launch_bounds__(256) void megaprep(
    const float* __restrict__ qa1w, const float* __restrict__ qa2w,
    const float* __restrict__ lin1w, const float* __restrict__ lin2w,
    ushort* __restrict__ qe1, ushort* __restrict__ qe2,
    ushort* __restrict__ l1w, ushort* __restrict__ l2w,
    const int* __restrict__ x, const float* __restrict__ e24,
    const float* __restrict__ e72, ushort* __restrict__ feat,
    const int* __restrict__ dst, int* __restrict__ bh) {
  int bid = blockIdx.x, t = threadIdx.x;
  if (bid < 256) {
    const float* qw = (bid < 128) ? qa1w : qa2w;
    ushort* eff = (bid < 128) ? qe1 : qe2;
    int k = (bid & 127) * 2 + (t >> 7);
    int j = t & 127;
    const float* r = qw + (size_t)k * 256;
    float v;
    if (j < 64) v = r[j] + r[128 + j] + r[192 + j];
    else { int j2 = j - 64; v = r[64 + j2] + r[128 + j2] + 2.0f * r[192 + j2]; }
    eff[(size_t)k * 128 + j] = f2bf(v);
  } else if (bid < 304) {
    int i = (bid - 256) * 256 + t;  // < 12288 = 128*96
    int r = i / 96, c = i - r * 96;
    l1w[i] = (c < 68) ? f2bf(lin1w[(size_t)r * 68 + c]) : (ushort)0;
  } else if (bid < 432) {
    int r = bid - 304;
    l2w[(size_t)r * 256 + t] = f2bf(lin2w[(size_t)r * 256 + t]);
  } else if (bid < 1456) {
    const int stride = 1024 * 256;
    for (int i = (bid - 432) * 256 + t; i < N_NODESC * 96; i += stride) {
      int n = i / 96, tt = i - n * 96;
      float v = 0.f;
      if (tt < 4) v = (float)x[n * 4 + tt];
      else if (tt < 36) { int kk = tt - 4;  int f = kk >> 3, c = kk & 7; v = e24[(x[n * 4 + f] % 24) * 8 + c]; }
      else if (tt < 68) { int kk = tt - 36; int f = kk >> 3, c = kk & 7; v = e72[(x[n * 4 + f] % 72) * 8 + c]; }
      feat[i] = f2bf(v);
    }
  } else {
    __shared__ int hist[NBIN];
    int blk = bid - 1456;
    if (t < NBIN) hist[t] = 0;
    __syncthreads();
    int base = blk * 4096;
#pragma unroll
    for (int i = 0; i < 16; ++i) {
      int idx = base + i * 256 + t;
      if (idx < N_EDGESC) atomicAdd(&hist[dst[idx] >> 8], 1);
    }
    __syncthreads();
    if (t < NBIN) bh[(size_t)t * NBLKE + blk] = hist[t];
  }
}

// ---------------- CSR build: bucketed two-pass sort ----------------
__global__ __launch_bounds__(64) void csr_scan_bins(int* __restrict__ bh, int* __restrict__ bt) {
  int bin = blockIdx.x;
  int lane = threadIdx.x;
  int carry = 0;
  int* row = bh + (size_t)bin * NBLKE;
  for (int c = 0; c < NBLKE; c += 64) {
    int j = c + lane;
    int v = (j < NBLKE) ? row[j] : 0;
    int incl = v;
#pragma unroll
    for (int off = 1; off < 64; off <<= 1) {
      int u = __shfl_up(incl, off, 64);
      if (lane >= off) incl += u;
    }
    if (j < NBLKE) row[j] = carry + incl - v;
    carry += __shfl(incl, 63, 64);
  }
  if (lane == 0) bt[bin] = carry;
}

// scatter packed edges into bucket-grouped tmp; bucket bases derived from bt in-block
__global__ __launch_bounds__(256) void csr_scatter(const int* __restrict__ src,
                                                   const int* __restrict__ dst,
                                                   const int* __restrict__ bh,
                                                   const int* __restrict__ bt,
                                                   uint* __restrict__ tmp, int E) {
  __shared__ int sc[256];
  __shared__ int cur[NBIN];
  int t = threadIdx.x, blk = blockIdx.x;
  int v = (t < NBIN) ? bt[t] : 0;
  sc[t] = v;
  __syncthreads();
  for (int off = 1; off < 256; off <<= 1) {
    int u = (t >= off) ? sc[t - off] : 0;
    __syncthreads();
    sc[t] += u;
    __syncthreads();
  }
  if (t < NBIN) cur[t] = (sc[t] - v) + bh[(size_t)t * NBLKE + blk];
  __syncthreads();
  int base = blk * 4096;
#pragma unroll
  for (int i = 0; i < 16; ++i) {
    int idx = base + i * 256 + t;
    if (idx < E) {
      int d = dst[idx];
      uint p = ((uint)d << 16) | (uint)src[idx];
      int pos = atomicAdd(&cur[d >> 8], 1);
      tmp[pos] = p;
    }
  }
}

// per-bucket counting sort by node -> elist (ushort src) + rp
__global__ __launch_bounds__(256) void csr_bucket_sort(const uint* __restrict__ tmp,
                                                       const int* __restrict__ bt,
                                                       ushort* __restrict__ elist,
                                                       int* __restrict__ rp) {
  __shared__ int sc[256];
  __shared__ int cnt[256];
  int b = blockIdx.x, t = threadIdx.x;
  int v = (t < NBIN) ? bt[t] : 0;
  sc[t] = v;
  __syncthreads();
  for (int off = 1; off < 256; off <<= 1) {
    int u = (t >= off) ? sc[t - off] : 0;
    __syncthreads();
    sc[t] += u;
    __syncthreads();
  }
  int base = (b == 0) ? 0 : sc[b - 1];
  int end = sc[b];
  int total = sc[NBIN - 1];
  __syncthreads();
  cnt[t] = 0;
  __syncthreads();
  for (int i = base + t; i < end; i += 256)
    atomicAdd(&cnt[(tmp[i] >> 16) & 255], 1);
  __syncthreads();
  int cv = cnt[t];
  sc[t] = cv;
  __syncthreads();
  for (int off = 1; off < 256; off <<= 1) {
    int u = (t >= off) ? sc[t - off] : 0;
    __syncthreads();
    sc[t] += u;
    __syncthreads();
  }
  int excl = sc[t] - cv;
  int node = (b << 8) + t;
  if (node < N_NODESC) rp[node] = base + excl;
  if (b == NBIN - 1 && t == 0) rp[N_NODESC] = total;
  cnt[t] = base + excl;  // global cursor
  __syncthreads();
  for (int i = base + t; i < end; i += 256) {
    uint p = tmp[i];
    int pos = atomicAdd(&cnt[(p >> 16) & 255], 1);
    elist[pos] = (ushort)(p & 0xFFFFu);
  }
}

// ---------------- MFMA GEMM with W staged in LDS ----------------------------
// C[M,NC] = act(A[M,K] @ W[NC,K]^T + b); grid (ceil(M/128), NC/128).
// W tile (128 cols x K) staged once in swizzled LDS, reused by all 4 waves.
template <int K>
__global__ __launch_bounds__(256, 2) void mfma_gemm_lds(
    const ushort* __restrict__ A, const ushort* __restrict__ W,
    const float* __restrict__ bias, ushort* __restrict__ C,
    int M, int NC, int relu) {
  __shared__ ushort ws[128 * K];
  int tid = threadIdx.x;
  int lane = tid & 63;
  int wv = tid >> 6;
  int rbase = blockIdx.x * 128 + wv * 32;
  int colt = blockIdx.y * 128;
  int r16 = lane & 15;
  int kg = (lane >> 4) * 8;

  // stage W tile: rows colt..colt+127 contiguous (128*K ushorts)
  const char* wt = (const char*)(W + (size_t)colt * K);
#pragma unroll
  for (int i = 0; i < K / 16; ++i) {
    int o = (i * 256 + tid) * 16;          // byte offset in tile
    int col = o / (2 * K);
    int sw = o ^ ((col & 7) << 4);
    *(bf16x8*)((char*)ws + sw) = *(const bf16x8*)(wt + o);
  }
  __syncthreads();

  f32x4 acc[2][8];
#pragma unroll
  for (int m = 0; m < 2; ++m)
#pragma unroll
    for (int n = 0; n < 8; ++n) acc[m][n] = (f32x4){0.f, 0.f, 0.f, 0.f};

  for (int k0 = 0; k0 < K; k0 += 32) {
    bf16x8 a[2], b[8];
#pragma unroll
    for (int m = 0; m < 2; ++m) {
      int rr = rbase + m * 16 + r16;
      if (rr >= M) rr = M - 1;
      a[m] = *(const bf16x8*)(A + (size_t)rr * K + k0 + kg);
    }
#pragma unroll
    for (int n = 0; n < 8; ++n) {
      int cl = n * 16 + r16;
      int byte = (cl * 2 * K + (k0 + kg) * 2) ^ ((cl & 7) << 4);
      b[n] = *(const bf16x8*)((const char*)ws + byte);
    }
#pragma unroll
    for (int m = 0; m < 2; ++m)
#pragma unroll
      for (int n = 0; n < 8; ++n)
        acc[m][n] = __builtin_amdgcn_mfma_f32_16x16x32_bf16(a[m], b[n], acc[m][n], 0, 0, 0);
  }

  int rowoff = (lane >> 4) * 4;
#pragma unroll
  for (int m = 0; m < 2; ++m) {
#pragma unroll
    for (int j = 0; j < 4; ++j) {
      int row = rbase + m * 16 + rowoff + j;
      if (row >= M) continue;
#pragma unroll
      for (int n = 0; n < 8; ++n) {
        int col = colt + n * 16 + r16;
        float v = acc[m][n][j] + bias[col];
        if (relu) v = fmaxf(v, 0.f);
        C[(size_t)row * NC + col] = f2bf(v);
      }
    }
  }
}

// ---------------- aggregation: h2[n] = 2*linx[n] + sum_{e->n} linx[src] -----
__global__ __launch_bounds__(256) void aggregate2(const uint* __restrict__ lx,
                                                  const int* __restrict__ rp,
                                                  const ushort* __restrict__ elist,
                                                  uint* __restrict__ h2) {
  int wv = threadIdx.x >> 6, lane = threadIdx.x & 63;
  int n = blockIdx.x * 4 + wv;
  int beg = rp[n], end = rp[n + 1];
  uint u = lx[(size_t)n * 64 + lane];
  float a0 = 2.f * bflo(u), a1 = 2.f * bfhi(u);
  int e = beg;
  for (; e + 8 <= end; e += 8) {
    int s0 = elist[e], s1 = elist[e + 1], s2 = elist[e + 2], s3 = elist[e + 3];
    int s4 = elist[e + 4], s5 = elist[e + 5], s6 = elist[e + 6], s7 = elist[e + 7];
    uint u0 = lx[(size_t)s0 * 64 + lane];
    uint u1 = lx[(size_t)s1 * 64 + lane];
    uint u2 = lx[(size_t)s2 * 64 + lane];
    uint u3 = lx[(size_t)s3 * 64 + lane];
    uint u4 = lx[(size_t)s4 * 64 + lane];
    uint u5 = lx[(size_t)s5 * 64 + lane];
    uint u6 = lx[(size_t)s6 * 64 + lane];
    uint u7 = lx[(size_t)s7 * 64 + lane];
    a0 += bflo(u0) + bflo(u1) + bflo(u2) + bflo(u3);
    a1 += bfhi(u0) + bfhi(u1) + bfhi(u2) + bfhi(u3);
    a0 += bflo(u4) + bflo(u5) + bflo(u6) + bflo(u7);
    a1 += bfhi(u4) + bfhi(u5) + bfhi(u6) + bfhi(u7);
  }
  for (; e < end; ++e) {
    uint u0 = lx[(size_t)elist[e] * 64 + lane];
    a0 += bflo(u0);
    a1 += bfhi(u0);
  }
  h2[(size_t)n * 64 + lane] = (uint)f2bf(a0) | ((uint)f2bf(a1) << 16);
}

// ---------------- global mean pool (batch sorted), bf16 input ---------------
__global__ __launch_bounds__(128) void pool2(const uint* __restrict__ h,
                                             const int* __restrict__ batch,
                                             float* __restrict__ g) {
  int gg = blockIdx.x;
  int j = threadIdx.x;
  int lo = 0, hi = N_NODESC;
  while (lo < hi) { int mid = (lo + hi) >> 1; if (batch[mid] < gg) lo = mid + 1; else hi = mid; }
  int beg = lo;
  hi = N_NODESC;
  while (lo < hi) { int mid = (lo + hi) >> 1; if (batch[mid] < gg + 1) lo = mid + 1; else hi = mid; }
  int end = lo;
  float a0 = 0.f, a1 = 0.f;
  for (int n = beg; n < end; ++n) {
    uint u = h[(size_t)n * 128 + j];
    a0 += bflo(u);
    a1 += bfhi(u);
  }
  float c = fmaxf((float)(end - beg), 1.0f);
  g[(size_t)gg * 256 + 2 * j] = a0 / c;
  g[(size_t)gg * 256 + 2 * j + 1] = a1 / c;
}

// ---------------- per-property heads (8 graphs per block) -------------------
__global__ __launch_bounds__(128) void head_kernel(const float* __restrict__ g,
    const float* __restrict__ w1, const float* __restrict__ b1,
    const float* __restrict__ w2, const float* __restrict__ b2,
    float* __restrict__ out) {
  int p = blockIdx.y;
  int g0 = blockIdx.x * 8;
  int t = threadIdx.x;
  __shared__ float gs[8][256];
  for (int i = t; i < 8 * 256; i += 128)
    gs[i >> 8][i & 255] = g[(size_t)(g0 + (i >> 8)) * 256 + (i & 255)];
  __syncthreads();
  const float4* w4 = (const float4*)(w1 + ((size_t)p * 128 + t) * 256);
  float bv = b1[p * 128 + t];
  float acc[8];
#pragma unroll
  for (int q = 0; q < 8; ++q) acc[q] = bv;
  for (int d4 = 0; d4 < 64; ++d4) {
    float4 wv = w4[d4];
#pragma unroll
    for (int q = 0; q < 8; ++q) {
      acc[q] += gs[q][d4 * 4 + 0] * wv.x + gs[q][d4 * 4 + 1] * wv.y +
                gs[q][d4 * 4 + 2] * wv.z + gs[q][d4 * 4 + 3] * wv.w;
    }
  }
  float w2v = w2[p * 128 + t];
  __shared__ float red[2][8];
  int wave = t >> 6, lane = t & 63;
#pragma unroll
  for (int q = 0; q < 8; ++q) {
    float v = fmaxf(acc[q], 0.f) * w2v;
    for (int o = 32; o > 0; o >>= 1) v += __shfl_down(v, o, 64);
    if (lane == 0) red[wave][q] = v;
  }
  __syncthreads();
  if (t < 8) out[(size_t)(g0 + t) * 8 + p] = red[0][t] + red[1][t] + b2[p];
}

extern "C" void kernel_launch(void* const* d_in, const int* in_sizes, int n_in,
                              void* d_out, int out_size, void* d_ws, size_t ws_size,
                              hipStream_t stream) {
  const int*   x     = (const int*)d_in[0];
  const int*   ei    = (const int*)d_in[1];
  const int*   batch = (const int*)d_in[2];
  const float* emb24 = (const float*)d_in[3];
  const float* emb72 = (const float*)d_in[4];
  const float* lin1w = (const float*)d_in[5];
  const float* lin1b = (const float*)d_in[6];
  const float* qa1w  = (const float*)d_in[7];
  const float* qa1b  = (const float*)d_in[8];
  const float* lin2w = (const float*)d_in[9];
  const float* lin2b = (const float*)d_in[10];
  const float* qa2w  = (const float*)d_in[11];
  const float* qa2b  = (const float*)d_in[12];
  const float* hw1   = (const float*)d_in[13];
  const float* hb1   = (const float*)d_in[14];
  const float* hw2   = (const float*)d_in[15];
  const float* hb2   = (const float*)d_in[16];
  float* out = (float*)d_out;

  const int* srcv = ei;
  const int* dstv = ei + N_EDGESC;

  char* wsb = (char*)d_ws;
  size_t off = 0;
  auto alloc = [&](size_t b) { char* p = wsb + off; off += (b + 255) & ~(size_t)255; return p; };
  ushort* feat  = (ushort*)alloc((size_t)N_NODESC * 96 * 2);
  ushort* linx  = (ushort*)alloc((size_t)N_NODESC * 128 * 2);   // row-major [N][128]
  ushort* h2    = (ushort*)alloc((size_t)N_NODESC * 128 * 2);   // row-major
  ushort* h     = (ushort*)alloc((size_t)N_NODESC * 256 * 2);   // row-major (layer-2 out)
  float*  gbuf  = (float*)alloc((size_t)NGC * 256 * 4);
  ushort* qe1   = (ushort*)alloc(256 * 128 * 2);
  ushort* qe2   = (ushort*)alloc(256 * 128 * 2);
  ushort* l1w   = (ushort*)alloc(128 * 96 * 2);
  ushort* l2w   = (ushort*)alloc(128 * 256 * 2);
  int*    rp    = (int*)alloc((size_t)(N_NODESC + 1) * 4);
  ushort* elist = (ushort*)alloc((size_t)N_EDGESC * 2);
  int*    bh    = (int*)alloc((size_t)NBIN * NBLKE * 4);
  int*    bt    = (int*)alloc((size_t)NBIN * 4);
  uint*   tmp   = (uint*)h;  // alias: h not written until qa2 (after CSR done)

  // fused prep: weights + features + histogram
  megaprep<<<1847, 256, 0, stream>>>(qa1w, qa2w, lin1w, lin2w, qe1, qe2, l1w, l2w,
                                     x, emb24, emb72, feat, dstv, bh);

  // CSR build: bucketed two-pass sort
  csr_scan_bins<<<NBIN, 64, 0, stream>>>(bh, bt);
  csr_scatter<<<NBLKE, 256, 0, stream>>>(srcv, dstv, bh, bt, tmp, N_EDGESC);
  csr_bucket_sort<<<NBIN, 256, 0, stream>>>(tmp, bt, elist, rp);

  int gm = (N_NODESC + 127) / 128;

  // layer 1
  mfma_gemm_lds<96><<<dim3(gm, 1), 256, 0, stream>>>(feat, l1w, lin1b, linx, N_NODESC, 128, 0);
  aggregate2<<<N_NODESC / 4, 256, 0, stream>>>((const uint*)linx, rp, elist, (uint*)h2);
  mfma_gemm_lds<128><<<dim3(gm, 2), 256, 0, stream>>>(h2, qe1, qa1b, h, N_NODESC, 256, 1);

  // layer 2
  mfma_gemm_lds<256><<<dim3(gm, 1), 256, 0, stream>>>(h, l2w, lin2b, linx, N_NODESC, 128, 0);
  aggregate2<<<N_NODESC / 4, 256, 0, stream>>>((const uint*)linx, rp, elist, (uint*)h2);
  mfma_gemm_lds<128><<<dim3(gm, 2), 256, 0, stream>>>(h2, qe2, qa2b, h, N_NODESC, 256, 1);

  // pool + heads
  pool2<<<NGC, 128, 0, stream>>>((const uint*)h, batch, gbuf);
  head_kernel<<<dim3(NGC / 8, NPC), 128, 0, stream>>>(gbuf, hw1, hb1, hw2, hb2, out);
}